// Round 13
// baseline (355.769 us; speedup 1.0000x reference)
//
#include <hip/hip_runtime.h>

// VQ-VAE forward, MI355X round 23: R22 + conv2m LDS entries re-strided
// 64B -> 80B (bank-safe 40-short stride, proven in d1m/vqm): kills the
// 8-way ds_read_b128 conflict (4.85M/dispatch measured). Same math.

typedef __attribute__((ext_vector_type(8))) short     short8;
typedef __attribute__((ext_vector_type(4))) short     s16x4;
typedef __attribute__((ext_vector_type(8))) __bf16    bf16x8;
typedef __attribute__((ext_vector_type(4))) float     f32x4;
typedef __attribute__((ext_vector_type(4))) unsigned  uint32x4;

__device__ __forceinline__ float b2f(unsigned short b) {
  union { unsigned u; float f; } v; v.u = ((unsigned)b) << 16; return v.f;
}
__device__ __forceinline__ unsigned short f2b(float f) {  // round-to-nearest-even
  union { float f; unsigned u; } v; v.f = f;
  unsigned r = v.u + 0x7FFF + ((v.u >> 16) & 1);
  return (unsigned short)(r >> 16);
}

// ---------------- fused weight/embed prep (all layers, 1 launch) ------------
__global__ __launch_bounds__(256) void prepall_k(
    const float* __restrict__ ew1, const float* __restrict__ ew2,
    const float* __restrict__ ew3, const float* __restrict__ dw1,
    const float* __restrict__ dw2, const float* __restrict__ dw3,
    const float* __restrict__ emb,
    unsigned short* __restrict__ wq1, unsigned short* __restrict__ wq2,
    unsigned short* __restrict__ wq3, unsigned short* __restrict__ wq4,
    unsigned short* __restrict__ wq5, unsigned short* __restrict__ wq6,
    unsigned short* __restrict__ wqe, float* __restrict__ eng) {
  const int b = blockIdx.x;
  if (b < 64) {                                   // prepe: 16384
    const int i = b*256 + threadIdx.x;
    const int j = i & 7, l = (i >> 3) & 63, ni = (i >> 9) & 3, nc = i >> 11;
    const int lm = l & 15, lk = l >> 4;
    wqe[i] = f2b(emb[(nc*64 + ni*16 + lm)*32 + lk*8 + j]);
    if (i < 512) {
      float s = 0.f;
      #pragma unroll
      for (int k = 0; k < 32; ++k) {
        const float f = b2f(f2b(emb[i*32 + k]));
        s = fmaf(f, f, s);
      }
      eng[i] = s;
    }
  } else if (b < 80) {                            // prep1v: 4096
    const int i = (b - 64)*256 + threadIdx.x;
    const int j = i & 7, l = (i >> 3) & 63, ni = (i >> 9) & 3, ks = i >> 11;
    const int k = ks*32 + (l >> 4)*8 + j;
    const int co = ni*16 + (l & 15);
    wq1[i] = (k < 48) ? f2b(ew1[co*48 + k]) : (unsigned short)0;
  } else if (b < 592) {                           // prep2v: 131072
    const int i = (b - 80)*256 + threadIdx.x;
    const int j = i & 7, l = (i >> 3) & 63, ni = (i >> 9) & 7, ks = i >> 12;
    const int lm = l & 15, lk = l >> 4;
    const int tap = ks >> 1, cc = ks & 1;
    const int co = ni*16 + lm, ci = cc*32 + lk*8 + j;
    wq2[i] = f2b(ew2[(co*64 + ci)*16 + tap]);
  } else if (b < 736) {                           // prep3v: 36864
    const int i = (b - 592)*256 + threadIdx.x;
    const int j = i & 7, l = (i >> 3) & 63, ni = (i >> 9) & 1, ks = i >> 10;
    const int lm = l & 15, lk = l >> 4;
    const int tap = ks >> 2, cf = ks & 3;
    const int co = ni*16 + lm, ci = cf*32 + lk*8 + j;
    wq3[i] = f2b(ew3[(co*128 + ci)*9 + tap]);
  } else if (b < 880) {                           // prep4v: 36864
    const int i = (b - 736)*256 + threadIdx.x;
    const int j = i & 7, l = (i >> 3) & 63, ni = (i >> 9) & 7, tap = i >> 12;
    const int lm = l & 15, lk = l >> 4;
    const int co = ni*16 + lm, ci = lk*8 + j;
    wq4[i] = f2b(dw1[(ci*128 + co)*9 + (8 - tap)]);
  } else if (b < 1392) {                          // prep5v: 131072
    const int i = (b - 880)*256 + threadIdx.x;
    const int j = i & 7, l = (i >> 3) & 63, ni = (i >> 9) & 3;
    const int ks = (i >> 11) & 15, p = i >> 15;
    const int lm = l & 15, lk = l >> 4;
    const int py = p >> 1, px = p & 1;
    const int a = ks >> 3, bb = (ks >> 2) & 1, cc = ks & 3;
    const int co = ni*16 + lm, ci = cc*32 + lk*8 + j;
    const int ky = 3 - 2*a - py, kx = 3 - 2*bb - px;
    wq5[i] = f2b(dw2[(ci*64 + co)*16 + ky*4 + kx]);
  } else {                                        // prep6: 16384
    const int i = (b - 1392)*256 + threadIdx.x;
    const int j = i & 7, l = (i >> 3) & 63, kc = (i >> 9) & 7, p = i >> 12;
    const int lm = l & 15, lk = l >> 4;
    const int a = kc >> 2, bb = (kc >> 1) & 1, ch = kc & 1;
    const int ci = ch*32 + lk*8 + j, co = lm;
    const int py = p >> 1, px = p & 1;
    const int ky = 2 - 2*a + (1 - py), kx = 2 - 2*bb + (1 - px);
    wq6[i] = (co < 3) ? f2b(dw3[(ci*3 + co)*16 + ky*4 + kx]) : (unsigned short)0;
  }
}

// ---- conv1 via MFMA: x NCHW fp32 [32,3,256,256] -> h1 NHWC bf16 ------------
__global__ __launch_bounds__(256) void conv1m_k(const float* __restrict__ x,
    const unsigned short* __restrict__ wv, const float* __restrict__ bias,
    unsigned short* __restrict__ out) {
  __shared__ __align__(16) short RAW[12*264];   // row g=ci*4+ky, idx=ix+4; 6336B
  __shared__ __align__(16) short IC[128*64];    // [ox][k] swizzled; 16384B
  const int wid = ((blockIdx.x & 7) << 9) + (blockIdx.x >> 3);
  const int q = wid & 127, n = wid >> 7;        // q = output row oy
  for (int i = threadIdx.x; i < 396; i += 256)
    *(short8*)&RAW[i*8] = (short8)(short)0;
  __syncthreads();
  for (int s = threadIdx.x; s < 768; s += 256) {   // 12 rows * 64 f32x4
    const int g = s >> 6, seg = s & 63;
    const int ci = g >> 2, ky = g & 3;
    const int iy = 2*q - 1 + ky;
    if (iy >= 0 && iy < 256) {
      const f32x4 v = *(const f32x4*)&x[((n*3 + ci)*256 + iy)*256 + seg*4];
      s16x4 sv;
      #pragma unroll
      for (int e = 0; e < 4; ++e) sv[e] = (short)f2b(v[e]);
      *(s16x4*)&RAW[g*264 + 4 + seg*4] = sv;
    }
  }
  __syncthreads();
  for (int s = threadIdx.x; s < 1024; s += 256) {
    const int kb = s & 7, ox = s >> 3;
    short8 v = (short8)(short)0;
    if (kb < 6) {
      const unsigned* u0 = (const unsigned*)&RAW[(2*kb  )*264 + 2*ox + 2];
      const unsigned* u1 = (const unsigned*)&RAW[(2*kb+1)*264 + 2*ox + 2];
      const unsigned a0 = u0[0], a1 = u0[1], a2 = u0[2];
      const unsigned b0 = u1[0], b1 = u1[1], b2 = u1[2];
      uint32x4 uv;
      uv[0] = (a0 >> 16) | (a1 << 16);
      uv[1] = (a1 >> 16) | (a2 << 16);
      uv[2] = (b0 >> 16) | (b1 << 16);
      uv[3] = (b1 >> 16) | (b2 << 16);
      v = __builtin_bit_cast(short8, uv);
    }
    const int bo = ((ox << 7) + (kb << 4)) ^ ((ox & 7) << 4);
    *(short8*)((char*)IC + bo) = v;
  }
  __syncthreads();
  const int w = threadIdx.x >> 6, l = threadIdx.x & 63;
  const int lm = l & 15, lk = l >> 4;
  f32x4 acc[2][4];
  #pragma unroll
  for (int mi = 0; mi < 2; ++mi)
    #pragma unroll
    for (int ni = 0; ni < 4; ++ni) acc[mi][ni] = (f32x4)0.0f;
  #pragma unroll
  for (int ks = 0; ks < 2; ++ks) {
    short8 bv[4];
    #pragma unroll
    for (int ni = 0; ni < 4; ++ni)
      bv[ni] = *(const short8*)(wv + (((ks*4 + ni)*64 + l) << 3));
    #pragma unroll
    for (int mi = 0; mi < 2; ++mi) {
      const int ox = w*32 + mi*16 + lm;
      const int bo = ((ox << 7) + (ks << 6) + (lk << 4)) ^ ((ox & 7) << 4);
      const short8 av = *(const short8*)((const char*)IC + bo);
      #pragma unroll
      for (int ni = 0; ni < 4; ++ni)
        acc[mi][ni] = __builtin_amdgcn_mfma_f32_16x16x32_bf16(
            __builtin_bit_cast(bf16x8, av),
            __builtin_bit_cast(bf16x8, bv[ni]),
            acc[mi][ni], 0, 0, 0);
    }
  }
  __syncthreads();            // frag reads done; reuse IC for output staging
  #pragma unroll
  for (int mi = 0; mi < 2; ++mi)
    #pragma unroll
    for (int ni = 0; ni < 4; ++ni) {
      const int co = ni*16 + lm;
      const float bv = bias[co];
      #pragma unroll
      for (int r = 0; r < 4; ++r) {
        const int ox = w*32 + mi*16 + lk*4 + r;
        const int bo = ((ox << 7) + 2*co) ^ ((ox & 7) << 4);
        *(short*)((char*)IC + bo) = (short)f2b(fmaxf(acc[mi][ni][r] + bv, 0.f));
      }
    }
  __syncthreads();
  const long ob = ((long)(n*128 + q)) * 8192;   // 128 ox * 64 co
  for (int s = threadIdx.x; s < 1024; s += 256) {
    const int kb = s & 7, ox = s >> 3;
    const int bo = ((ox << 7) + (kb << 4)) ^ ((ox & 7) << 4);
    *(short8*)&out[ob + ox*64 + kb*8] = *(const short8*)((const char*)IC + bo);
  }
}

// ---- conv2 via two-phase MFMA + async stage: h1 -> h2 ----------------------
//      IL entries 80B stride (bank-safe): A-read lane (lm,lk) -> bank
//      (20*lm + 4*lk) mod 32 = 8 distinct quads x 2-way = conflict-free.
#define C2_LOAD(c) \
  _Pragma("unroll") \
  for (int s = 0; s < 9; ++s) { \
    st[s] = (short8)(short)0; \
    if (goff[s] >= 0) st[s] = *(const short8*)(in + goff[s] + (c)*32); \
  }
#define C2_WRITE \
  _Pragma("unroll") \
  for (int s = 0; s < 9; ++s) \
    if (lb[s] >= 0) *(short8*)((char*)IL + lb[s]) = st[s];
#define C2_COMPUTE(c) \
  _Pragma("unroll") \
  for (int t = 0; t < 16; ++t) { \
    const int ky = t >> 2, kx = t & 3; \
    const int p = 1 - (kx & 1), d = kx >> 1; \
    const short8 bv0 = *(const short8*)(wb + (t*2 + (c))*4096); \
    const short8 bv1 = *(const short8*)(wb + (t*2 + (c))*4096 + 512); \
    const char* Ab = (const char*)IL + (Bd0 + d*80); \
    const int imm0 = (ky*2 + p)*5280; \
    _Pragma("unroll") \
    for (int mi = 0; mi < 4; ++mi) { \
      const short8 av = *(const short8*)(Ab + imm0 + mi*1280); \
      acc[mi][0] = __builtin_amdgcn_mfma_f32_16x16x32_bf16( \
          __builtin_bit_cast(bf16x8, av), __builtin_bit_cast(bf16x8, bv0), \
          acc[mi][0], 0, 0, 0); \
      acc[mi][1] = __builtin_amdgcn_mfma_f32_16x16x32_bf16( \
          __builtin_bit_cast(bf16x8, av), __builtin_bit_cast(bf16x8, bv1), \
          acc[mi][1], 0, 0, 0); \
    } \
  }
__global__ __launch_bounds__(256) void conv2m_k(const unsigned short* __restrict__ in,
    const unsigned short* __restrict__ wv, const float* __restrict__ bias,
    unsigned short* __restrict__ out) {
  __shared__ short IL[528*40];         // 528 entries x 80 B, 42240 B
  const int wid = (blockIdx.x & 7)*256 + (blockIdx.x >> 3);
  const int q = wid & 63, n = wid >> 6;          // q = output row oy
  const int w = threadIdx.x >> 6, l = threadIdx.x & 63;
  const int lm = l & 15, lk = l >> 4;
  const int Bd0 = lm*80 + lk*16;                 // A-read byte base, d=0
  const unsigned short* wb = wv + w*1024 + l*8;  // + ks*4096 (+512 for ni=1)
  int goff[9], lb[9];
  #pragma unroll
  for (int s = 0; s < 9; ++s) {
    const int i = threadIdx.x + s*256;
    const int part = i & 3, e = i >> 2;
    const int idx = e % 66, rp = e / 66;
    const int r = rp >> 1, p = rp & 1;
    const int iy = 2*q - 1 + r, ix = 2*idx - p;
    const bool ok = (i < 2112) && iy >= 0 && iy < 128 && ix >= 0 && ix < 128;
    goff[s] = ok ? (((n*128 + iy)*128 + ix)*64 + part*8) : -1;
    lb[s]   = (i < 2112) ? (e*80 + part*16) : -1;
  }
  f32x4 acc[4][2];
  #pragma unroll
  for (int mi = 0; mi < 4; ++mi)
    #pragma unroll
    for (int ni = 0; ni < 2; ++ni) acc[mi][ni] = (f32x4)0.0f;
  short8 st[9];
  C2_LOAD(0); C2_WRITE;
  __syncthreads();
  C2_LOAD(1);                          // issue phase-1 loads (in flight)
  C2_COMPUTE(0);
  __syncthreads();                     // phase-0 LDS reads done
  C2_WRITE;                            // waits vmcnt for st, writes LDS
  __syncthreads();
  C2_COMPUTE(1);
  // coalesced epilogue: PB[64 ox][144 shorts] over IL (18432 B)
  __syncthreads();                     // compute(1) IL reads done
  short* PB = (short*)IL;
  #pragma unroll
  for (int mi = 0; mi < 4; ++mi)
    #pragma unroll
    for (int r = 0; r < 4; ++r) {
      const int ox = mi*16 + lk*4 + r;
      #pragma unroll
      for (int ni = 0; ni < 2; ++ni) {
        const int co = (w*2 + ni)*16 + lm;
        PB[ox*144 + co] = (short)f2b(fmaxf(acc[mi][ni][r] + bias[co], 0.f));
      }
    }
  __syncthreads();
  {
    const int pos = threadIdx.x >> 2, coq = (threadIdx.x & 3) << 5;
    const long ob = ((long)((n*64 + q)*64 + pos))*128 + coq;
    #pragma unroll
    for (int u2 = 0; u2 < 4; ++u2)
      *(short8*)&out[ob + u2*8] = *(const short8*)&PB[pos*144 + coq + u2*8];
  }
}

// ---- conv3 + fused VQ: h2 NHWC bf16 [32,64,64,128] -> zq f32 + loss --------
#define C3_LOAD(c) \
  _Pragma("unroll") \
  for (int s = 0; s < 9; ++s) { \
    st[s] = (short8)(short)0; \
    if (goff[s] >= 0) st[s] = *(const short8*)(in + goff[s] + (c)*64); \
  }
#define C3_WRITE \
  _Pragma("unroll") \
  for (int s = 0; s < 9; ++s) \
    if (lb[s] >= 0) *(short8*)((char*)IL + lb[s]) = st[s];
#define C3_COMPUTE(c) \
  _Pragma("unroll") \
  for (int u = 0; u < 18; ++u) { \
    const int tap = u >> 1, cc = u & 1; \
    const int ky = tap / 3, kx = tap % 3; \
    const int ks = tap*4 + (c)*2 + cc; \
    const short8 bv0 = *(const short8*)(wb + ks*1024); \
    const short8 bv1 = *(const short8*)(wb + ks*1024 + 512); \
    const char* Ab = (const char*)IL + (Wc[kx][cc]); \
    const int imm0 = ky*8448; \
    _Pragma("unroll") \
    for (int mi = 0; mi < 2; ++mi) { \
      const short8 av = *(const short8*)(Ab + imm0 + mi*2048); \
      acc[mi][0] = __builtin_amdgcn_mfma_f32_16x16x32_bf16( \
          __builtin_bit_cast(bf16x8, av), __builtin_bit_cast(bf16x8, bv0), \
          acc[mi][0], 0, 0, 0); \
      acc[mi][1] = __builtin_amdgcn_mfma_f32_16x16x32_bf16( \
          __builtin_bit_cast(bf16x8, av), __builtin_bit_cast(bf16x8, bv1), \
          acc[mi][1], 0, 0, 0); \
    } \
  }
__global__ __launch_bounds__(256) void conv3v_k(const unsigned short* __restrict__ in,
    const unsigned short* __restrict__ wv, const float* __restrict__ bias,
    const unsigned short* __restrict__ wqe, const float* __restrict__ eng,
    const float* __restrict__ emb, float* __restrict__ zq,
    float* __restrict__ part) {
  __shared__ short IL[4*66*64];        // 33792 B; unions below after compute
  const int wid = (blockIdx.x & 7)*128 + (blockIdx.x >> 3);
  const int q = wid & 31, n = wid >> 5;          // oy0 = 2q
  const int w = threadIdx.x >> 6, l = threadIdx.x & 63;
  const int lm = l & 15, lk = l >> 4;
  const int row = w >> 1, oxb = (w & 1) * 32;
  int goff[9], lb[9];
  #pragma unroll
  for (int s = 0; s < 9; ++s) {
    const int i = threadIdx.x + s*256;
    const int part_ = i & 7, e = i >> 3;
    const int col = e % 66, r = e / 66;
    const int iy = 2*q - 1 + r, ix = col - 1;
    const bool ok = (i < 2112) && iy >= 0 && iy < 64 && ix >= 0 && ix < 64;
    goff[s] = ok ? (((n*64 + iy)*64 + ix)*128 + part_*8) : -1;
    lb[s]   = (i < 2112) ? ((e << 7) + ((part_ << 4) ^ ((col & 7) << 4))) : -1;
  }
  int Wc[3][2];
  #pragma unroll
  for (int kx = 0; kx < 3; ++kx) {
    const int e = oxb + lm + kx;
    Wc[kx][0] = row*8448 + (e << 7) + ((lk << 4) ^ ((e & 7) << 4));
    Wc[kx][1] = Wc[kx][0] ^ 0x40;
  }
  const unsigned short* wb = wv + l*8;           // + ks*1024 + ni*512
  f32x4 acc[2][2];
  #pragma unroll
  for (int mi = 0; mi < 2; ++mi)
    #pragma unroll
    for (int ni = 0; ni < 2; ++ni) acc[mi][ni] = (f32x4)0.0f;
  short8 st[9];
  C3_LOAD(0); C3_WRITE;
  __syncthreads();
  C3_LOAD(1);
  C3_COMPUTE(0);
  __syncthreads();
  C3_WRITE;
  __syncthreads();
  C3_COMPUTE(1);
  // ---- fused VQ ----
  __syncthreads();                               // all IL reads done
  short* ZB  = (short*)IL;                       // [128][40] bf16, 10240 B
  float* ZF  = (float*)((char*)IL + 10240);      // [128][36] f32, 18432 B
  int*  bidx = (int*)((char*)IL + 28672);        // 128 ints
  float* red = (float*)((char*)IL + 29184);      // 256 floats
  #pragma unroll
  for (int mi = 0; mi < 2; ++mi)
    #pragma unroll
    for (int ni = 0; ni < 2; ++ni) {
      const int co = ni*16 + lm;
      const float bv = bias[co];
      #pragma unroll
      for (int r = 0; r < 4; ++r) {
        const int pos = row*64 + oxb + mi*16 + lk*4 + r;
        const float v = fmaxf(acc[mi][ni][r] + bv, 0.f);
        ZB[pos*40 + co] = (short)f2b(v);
        ZF[pos*36 + co] = v;
      }
    }
  __syncthreads();
  short8 av[2];
  #pragma unroll
  for (int mi = 0; mi < 2; ++mi)
    av[mi] = *(const short8*)&ZB[(row*64 + oxb + mi*16 + lm)*40 + lk*8];
  float bd[2][4]; int bj[2][4];
  #pragma unroll
  for (int mi = 0; mi < 2; ++mi)
    #pragma unroll
    for (int r = 0; r < 4; ++r) { bd[mi][r] = 1e30f; bj[mi][r] = 0; }
  for (int nc = 0; nc < 8; ++nc) {               // chunks of 64 codes
    f32x4 a2[2][4];
    #pragma unroll
    for (int mi = 0; mi < 2; ++mi)
      #pragma unroll
      for (int ni = 0; ni < 4; ++ni) a2[mi][ni] = (f32x4)0.0f;
    #pragma unroll
    for (int ni = 0; ni < 4; ++ni) {
      const short8 bv = *(const short8*)(wqe + (((nc*4 + ni)*64 + l) << 3));
      #pragma unroll
      for (int mi = 0; mi < 2; ++mi)
        a2[mi][ni] = __builtin_amdgcn_mfma_f32_16x16x32_bf16(
            __builtin_bit_cast(bf16x8, av[mi]),
            __builtin_bit_cast(bf16x8, bv),
            a2[mi][ni], 0, 0, 0);
    }
    #pragma unroll
    for (int ni = 0; ni < 4; ++ni) {
      const int j = nc*64 + ni*16 + lm;
      const float e_n = eng[j];
      #pragma unroll
      for (int mi = 0; mi < 2; ++mi)
        #pragma unroll
        for (int r = 0; r < 4; ++r) {
          const float d = fmaf(-2.f, a2[mi][ni][r], e_n);
          if (d < bd[mi][r]) { bd[mi][r] = d; bj[mi][r] = j; }
        }
    }
  }
  #pragma unroll
  for (int mi = 0; mi < 2; ++mi)
    #pragma unroll
    for (int r = 0; r < 4; ++r) {
      float d = bd[mi][r]; int j = bj[mi][r];
      #pragma unroll
      for (int off = 1; off < 16; off <<= 1) {
        const float od = __shfl_xor(d, off);
        const int   oj = __shfl_xor(j, off);
        if (od < d || (od == d && oj < j)) { d = od; j = oj; }
      }
      if (lm == 0) bidx[row*64 + oxb + mi*16 + lk*4 + r] = j;
    }
  __syncthreads();
  const int pl = threadIdx.x >> 1, hf = (threadIdx.x & 1) * 16;
  const int code = bidx[pl];
  const int oy2 = 2*q + (pl >> 6), ox2 = pl & 63;
  const long zqo = ((long)((n*64 + oy2)*64 + ox2)) * 32 + hf;
  float se = 0.f;
  #pragma unroll
  for (int qq = 0; qq < 4; ++qq) {
    const f32x4 ev = *(const f32x4*)&emb[code*32 + hf + qq*4];
    const f32x4 zv = *(const f32x4*)&ZF[pl*36 + hf + qq*4];
    *(f32x4*)&zq[zqo + qq*4] = ev;
    const f32x4 df = ev - zv;
    #pragma unroll
    for (int e = 0; e < 4; ++e) se = fmaf(df[e], df[e], se);
  }
  red[threadIdx.x] = se; __syncthreads();
  for (int s2 = 128; s2 > 0; s2 >>= 1) {
    if (threadIdx.x < s2) red[threadIdx.x] += red[threadIdx.x + s2];
    __syncthreads();
  }
  if (threadIdx.x == 0) part[blockIdx.x] = red[0];
}

// ---- d1 convT via MFMA: zq f32 [131072,32] -> d1 NHWC bf16 [32,64,64,128]
__global__ __launch_bounds__(256) void d1m_k(const float* __restrict__ in,
    const unsigned short* __restrict__ wv, const float* __restrict__ bias,
    unsigned short* __restrict__ out) {
  __shared__ short IL[264*40];         // [r*66+col][40-short stride], 21120 B
  const int wid = (blockIdx.x & 7)*128 + (blockIdx.x >> 3);
  const int q = wid & 31, n = wid >> 5;
  const int w = threadIdx.x >> 6, l = threadIdx.x & 63;
  const int lm = l & 15, lk = l >> 4;
  const int row = w >> 1, oxb = (w & 1) * 32;
  for (int i = threadIdx.x; i < 1056; i += 256) {  // 264 entries * 4 parts
    const int part = i & 3, e = i >> 2;
    const int col = e % 66, r = e / 66;
    const int iy = 2*q - 1 + r, ix = col - 1;
    short8 v = (short8)(short)0;
    if (iy >= 0 && iy < 64 && ix >= 0 && ix < 64) {
      const float* p = in + (((long)((n*64 + iy)*64 + ix)) * 32 + part*8);
      const f32x4 f0 = *(const f32x4*)p;
      const f32x4 f1 = *(const f32x4*)(p + 4);
      #pragma unroll
      for (int e2 = 0; e2 < 4; ++e2) {
        v[e2]     = (short)f2b(f0[e2]);
        v[e2 + 4] = (short)f2b(f1[e2]);
      }
    }
    *(short8*)&IL[e*40 + part*8] = v;
  }
  const unsigned short* wb = wv + l*8;             // + (tap*8+ni)*512
  int Wd[3];
  #pragma unroll
  for (int kx = 0; kx < 3; ++kx)
    Wd[kx] = row*5280 + (oxb + lm + kx)*80 + lk*16;   // bytes
  __syncthreads();
  f32x4 acc[2][8];
  #pragma unroll
  for (int mi = 0; mi < 2; ++mi)
    #pragma unroll
    for (int ni = 0; ni < 8; ++ni) acc[mi][ni] = (f32x4)0.0f;
  #pragma unroll
  for (int tap = 0; tap < 9; ++tap) {
    const int ky = tap / 3, kx = tap % 3;
    short8 bv[8];
    #pragma unroll
    for (int ni = 0; ni < 8; ++ni)
      bv[ni] = *(const short8*)(wb + (tap*8 + ni)*512);
    const char* Ab = (const char*)IL + Wd[kx];
    const int imm0 = ky*5280;
    #pragma unroll
    for (int mi = 0; mi < 2; ++mi) {
      const short8 av = *(const short8*)(Ab + imm0 + mi*1280);
      #pragma unroll
      for (int ni = 0; ni < 8; ++ni)
        acc[mi][ni] = __builtin_amdgcn_mfma_f32_16x16x32_bf16(
            __builtin_bit_cast(bf16x8, av),
            __builtin_bit_cast(bf16x8, bv[ni]),
            acc[mi][ni], 0, 0, 0);
    }
  }
  // coalesced epilogue: 2 row passes, PB[64 ox][144 shorts] over IL (18432 B)
  short* PB = (short*)IL;
  #pragma unroll
  for (int rp = 0; rp < 2; ++rp) {
    __syncthreads();                   // IL reads / prior pass reads done
    if (row == rp) {
      #pragma unroll
      for (int mi = 0; mi < 2; ++mi)
        #pragma unroll
        for (int r = 0; r < 4; ++r) {
          const int ox = oxb + mi*16 + lk*4 + r;
          #pragma unroll
          for (int ni = 0; ni < 8; ++ni) {
            const int co = ni*16 + lm;
            PB[ox*144 + co] = (short)f2b(fmaxf(acc[mi][ni][r] + bias[co], 0.f));
          }
        }
    }
    __syncthreads();
    const int pos = threadIdx.x >> 2, coq = (threadIdx.x & 3) << 5;
    const long ob = ((long)((n*64 + 2*q + rp)*64 + pos))*128 + coq;
    #pragma unroll
    for (int u2 = 0; u2 < 4; ++u2)
      *(short8*)&out[ob + u2*8] = *(const short8*)&PB[pos*144 + coq + u2*8];
  }
}

// ---- d2 convT: q-pair / 8-wave merged-parity MFMA + async stage ------------
__device__ __forceinline__ int ct2_goff(int i, int q0, int n) {
  const int part = i & 7, e = i >> 3;
  const int col = e % 66, r = e / 66;
  const int iy = q0 - 1 + r, ix = col - 1;
  return (i < 2112 && iy >= 0 && iy < 64 && ix >= 0 && ix < 64)
         ? (((n*64 + iy)*64 + ix)*128 + part*8) : -1;
}
__device__ __forceinline__ int ct2_lb(int i) {
  const int part = i & 7, e = i >> 3;
  const int col = e % 66;
  return (i < 2112) ? ((e << 7) + ((part << 4) ^ ((col & 7) << 4))) : -1;
}
#define CT2_LOAD(c) \
  _Pragma("unroll") \
  for (int s = 0; s < 5; ++s) { \
    const int g = ct2_goff(tid + s*512, q0, n); \
    st[s] = (short8)(short)0; \
    if (g >= 0) st[s] = *(const short8*)(in + g + (c)*64); \
  }
#define CT2_WRITE \
  _Pragma("unroll") \
  for (int s = 0; s < 5; ++s) { \
    const int b_ = ct2_lb(tid + s*512); \
    if (b_ >= 0) *(short8*)((char*)IL + b_) = st[s]; \
  }
#define CT2_COMPUTE(c) \
  _Pragma("unroll") \
  for (int u = 0; u < 8; ++u) { \
    const int a = u >> 2, b = (u >> 1) & 1, c1 = u & 1; \
    const int ks = (a << 3) | (b << 2) | (2*(c) + c1); \
    short8 bv[4]; \
    _Pragma("unroll") \
    for (int ni = 0; ni < 4; ++ni) \
      bv[ni] = *(const short8*)(wb + ks*2048 + ni*512); \
    const char* Ab = (const char*)IL + (pyb + Wb[b][c1]); \
    const int imm0 = a*8448; \
    _Pragma("unroll") \
    for (int mi = 0; mi < 4; ++mi) { \
      const short8 av = *(const short8*)(Ab + imm0 + mi*2048); \
      _Pragma("unroll") \
      for (int ni = 0; ni < 4; ++ni) \
        acc[mi][ni] = __builtin_amdgcn_mfma_f32_16x16x32_bf16( \
            __builtin_bit_cast(bf16x8, av), \
            __builtin_bit_cast(bf16x8, bv[ni]), \
            acc[mi][ni], 0, 0, 0); \
    } \
  }
__global__ __launch_bounds__(512, 4) void convt2m_k(
    const unsigned short* __restrict__ in,
    const unsigned short* __restrict__ wv, const float* __restrict__ bias,
    unsigned short* __restrict__ out) {
  __shared__ short IL[4*66*64];        // 264 entries x 128 B, 33792 B
  const int wid = (blockIdx.x & 7)*128 + (blockIdx.x >> 3);
  const int qp = wid & 31, n = wid >> 5;
  const int q0 = 2*qp;
  const int tid = threadIdx.x;
  const int w = tid >> 6, l = tid & 63;
  const int qi = w >> 2;
  const int py = (w >> 1) & 1, px = w & 1;
  const int lm = l & 15, lk = l >> 4;
  int Wb[2][2];
  #pragma unroll
  for (int b = 0; b < 2; ++b) {
    const int e = lm + px + b;
    Wb[b][0] = (e << 7) + ((lk << 4) ^ ((e & 7) << 4));
    Wb[b][1] = Wb[b][0] ^ 0x40;
  }
  const int pyb = (py + qi) * 8448;                // staged-row base
  const unsigned short* wb = wv + (w & 3)*32768 + l*8;   // parity weights
  f32x4 acc[4][4];
  #pragma unroll
  for (int mi = 0; mi < 4; ++mi)
    #pragma unroll
    for (int ni = 0; ni < 4; ++ni) acc[mi][ni] = (f32x4)0.0f;
  short8 st[5];
  CT2_LOAD(0); CT2_WRITE;
  __syncthreads();
  CT2_LOAD(1);                         // issue phase-1 loads (in flight)
  CT2_COMPUTE(0);
  __syncthreads();                     // phase-0 LDS reads done
  CT2_WRITE;                           // waits vmcnt, writes LDS
  __syncthreads();
  CT2_COMPUTE(1);
  // coalesced epilogue: 4 passes (qq x co-half), PB[256 pos][40 shorts]
  short* PB = (short*)IL;
  #pragma unroll
  for (int qq = 0; qq < 2; ++qq)
    #pragma unroll
    for (int half = 0; half < 2; ++half) {
      __syncthreads();                 // IL / prior-pass reads done
      if (qi == qq) {
        #pragma unroll
        for (int mi = 0; mi < 4; ++mi)
          #pragma unroll
          for (int r = 0; r < 4; ++r) {
            const int ox = 2*(mi*16 + lk*4 + r) + px;
            const int pos = py*128 + ox;
            #pragma unroll
            for (int nn = 0; nn < 2; ++nn) {
              const int co = (half*2 + nn)*16 + lm;
              PB[pos*40 + (co & 31)] =
                  (short)f2b(fmaxf(acc[mi][half*2 + nn][r] + bias[co], 0.f));
            }
          }
      }
      __syncthreads();
      const int pos = tid >> 1, hh = (tid & 1) << 4;
      const long ob = ((long)((n*128 + 2*(q0 + qq) + (pos >> 7))*128
                              + (pos & 127)))*64 + half*32 + hh;
      *(short8*)&out[ob]     = *(const short8*)&PB[pos*40 + hh];
      *(short8*)&out[ob + 8] = *(const short8*)&PB[pos*40 + hh + 8];
    }
}

__global__ __launch_bounds__(256) void loss_k(const float* __restrict__ part,
                                              float* __restrict__ out) {
  __shared__ float red[256];
  const int t = threadIdx.x;
  float s = 0.f;
  #pragma unroll
  for (int q = 0; q < 4; ++q) s += part[t + q*256];   // 1024 partials
  red[t] = s; __syncthreads();
  for (int st = 128; st > 0; st >>= 1) {
    if (t < st) red[t] += red[t + st];
    __syncthreads();
  }
  if (t == 0) out[0] = red[0] * (1.25f / (131072.f * 32.f));
}

// ---- convt3 via MFMA: d2 NHWC bf16 [32,128,128,64] -> x_recon NCHW fp32 ----
__global__ __launch_bounds__(256) void convt3m_k(const unsigned short* __restrict__ in,
    const unsigned short* __restrict__ wq6, const float* __restrict__ bias,
    float* __restrict__ out) {
  __shared__ short8 IL[3*8*66];      // [(r*8+c8)*66 + ixl], 25344 B
  const int h = blockIdx.x & 1, q = (blockIdx.x >> 1) & 127, n = blockIdx.x >> 8;
  for (int i = threadIdx.x; i < 1584; i += 256) {   // 3*66*8
    const int c8 = i & 7, t = i >> 3, ixl = t % 66, r = t / 66;
    const int iy = q - 1 + r, ix = h*64 - 1 + ixl;
    short8 v = (short8)(short)0;
    if (iy >= 0 && iy < 128 && ix >= 0 && ix < 128)
      v = *(const short8*)(in + (((long)(n*128 + iy)*128 + ix)*64 + c8*8));
    IL[(r*8 + c8)*66 + ixl] = v;
  }
  const int w = threadIdx.x >> 6, l = threadIdx.x & 63;
  const int py = w >> 1, px = w & 1;
  const int lm = l & 15, lk = l >> 4;
  short8 bfrag[8];
  #pragma unroll
  for (int kc = 0; kc < 8; ++kc)
    bfrag[kc] = *(const short8*)(wq6 + (((w*8 + kc)*64 + l) << 3));
  __syncthreads();
  f32x4 acc[4];
  #pragma unroll
  for (int mi = 0; mi < 4; ++mi) acc[mi] = (f32x4)0.0f;
  #pragma unroll
  for (int kc = 0; kc < 8; ++kc) {
    const int a = kc >> 2, b = (kc >> 1) & 1, ch = kc & 1;
    const int base = (((py + a)*8 + ch*4 + lk)*66) + px + b;   // + ixl(xq)
    #pragma unroll
    for (int mi = 0; mi < 4; ++mi) {
      const short8 av = *(const short8*)&IL[base + mi*16 + lm];
      acc[mi] = __builtin_amdgcn_mfma_f32_16x16x32_bf16(
          __builtin_bit_cast(bf16x8, av),
          __builtin_bit_cast(bf16x8, bfrag[kc]),
          acc[mi], 0, 0, 0);
    }
  }
  // coalesced epilogue via LDS (768 floats over IL)
  __syncthreads();                     // IL reads done
  float* PB3 = (float*)IL;
  if (lm < 3) {
    const float bv = bias[lm];
    #pragma unroll
    for (int mi = 0; mi < 4; ++mi)
      #pragma unroll
      for (int r = 0; r < 4; ++r) {
        const int xq = mi*16 + lk*4 + r;
        PB3[(lm*2 + py)*128 + 2*xq + px] = acc[mi][r] + bv;
      }
  }
  __syncthreads();
  for (int t = threadIdx.x; t < 768; t += 256) {
    const int co = t >> 8, rem = t & 255, pyl = rem >> 7, xx = rem & 127;
    out[((long)(n*3 + co))*65536 + (2*q + pyl)*256 + h*128 + xx] = PB3[t];
  }
}

extern "C" void kernel_launch(void* const* d_in, const int* in_sizes, int n_in,
                              void* d_out, int out_size, void* d_ws, size_t ws_size,
                              hipStream_t stream) {
  const float* x   = (const float*)d_in[0];
  const float* ew1 = (const float*)d_in[1];  const float* eb1 = (const float*)d_in[2];
  const float* ew2 = (const float*)d_in[3];  const float* eb2 = (const float*)d_in[4];
  const float* ew3 = (const float*)d_in[5];  const float* eb3 = (const float*)d_in[6];
  const float* emb = (const float*)d_in[7];
  const float* dw1 = (const float*)d_in[8];  const float* db1 = (const float*)d_in[9];
  const float* dw2 = (const float*)d_in[10]; const float* db2 = (const float*)d_in[11];
  const float* dw3 = (const float*)d_in[12]; const float* db3 = (const float*)d_in[13];
  float* out = (float*)d_out;

  uint8_t* w8 = (uint8_t*)d_ws;
  unsigned short* h1 = (unsigned short*)w8;
  unsigned short* h2 = (unsigned short*)(w8 + 67108864);
  uint8_t* zr = w8 + 100663296;
  float* zq  = (float*)(w8 + 117440512);
  unsigned short* wqe = (unsigned short*)zr;                  // 32768 B
  float* eng = (float*)(zr + 32768);                          // 2048 B
  float* part = (float*)(zr + 36864);                         // 4096 B
  unsigned short* wq3 = (unsigned short*)(zr + 40960);        // 73728 B
  unsigned short* wq4 = (unsigned short*)(zr + 131072);       // 73728 B
  unsigned short* wq5 = (unsigned short*)(zr + 262144);       // 262144 B
  unsigned short* wq6 = (unsigned short*)(zr + 524288);       // 32768 B
  unsigned short* wq2 = (unsigned short*)(w8 + 117440512);            // 262144 B
  unsigned short* wq1 = (unsigned short*)(w8 + 117440512 + 335872);   // 8192 B
  unsigned short* d1 = h2;
  unsigned short* d2 = h1;

  // all weight/embed prep in one launch
  prepall_k<<<dim3(1456),256,0,stream>>>(ew1, ew2, ew3, dw1, dw2, dw3, emb,
                                         wq1, wq2, wq3, wq4, wq5, wq6, wqe, eng);
  // encoder + fused VQ
  conv1m_k<<<dim3(4096),256,0,stream>>>(x, wq1, eb1, h1);
  conv2m_k<<<dim3(2048),256,0,stream>>>(h1, wq2, eb2, h2);
  conv3v_k<<<dim3(1024),256,0,stream>>>(h2, wq3, eb3, wqe, eng, emb, zq, part);
  loss_k<<<dim3(1),256,0,stream>>>(part, out + 6291456);
  // decoder
  d1m_k<<<dim3(1024),256,0,stream>>>(zq, wq4, db1, d1);
  convt2m_k<<<dim3(1024),512,0,stream>>>(d1, wq5, db2, d2);
  convt3m_k<<<dim3(8192),256,0,stream>>>(d2, wq6, db3, out);
}

// Round 14
// 343.608 us; speedup vs baseline: 1.0354x; 1.0354x over previous
//
#include <hip/hip_runtime.h>

// VQ-VAE forward, MI355X round 24: conv2m rebuilt on the PROVEN zero-conflict
// LDS layout (128B paired-parity entries + 3-bit XOR slot swizzle, as in
// convt2m/conv3v). LDS back to 33.8KB. Same math/order -> identical absmax.

typedef __attribute__((ext_vector_type(8))) short     short8;
typedef __attribute__((ext_vector_type(4))) short     s16x4;
typedef __attribute__((ext_vector_type(8))) __bf16    bf16x8;
typedef __attribute__((ext_vector_type(4))) float     f32x4;
typedef __attribute__((ext_vector_type(4))) unsigned  uint32x4;

__device__ __forceinline__ float b2f(unsigned short b) {
  union { unsigned u; float f; } v; v.u = ((unsigned)b) << 16; return v.f;
}
__device__ __forceinline__ unsigned short f2b(float f) {  // round-to-nearest-even
  union { float f; unsigned u; } v; v.f = f;
  unsigned r = v.u + 0x7FFF + ((v.u >> 16) & 1);
  return (unsigned short)(r >> 16);
}

// ---------------- fused weight/embed prep (all layers, 1 launch) ------------
__global__ __launch_bounds__(256) void prepall_k(
    const float* __restrict__ ew1, const float* __restrict__ ew2,
    const float* __restrict__ ew3, const float* __restrict__ dw1,
    const float* __restrict__ dw2, const float* __restrict__ dw3,
    const float* __restrict__ emb,
    unsigned short* __restrict__ wq1, unsigned short* __restrict__ wq2,
    unsigned short* __restrict__ wq3, unsigned short* __restrict__ wq4,
    unsigned short* __restrict__ wq5, unsigned short* __restrict__ wq6,
    unsigned short* __restrict__ wqe, float* __restrict__ eng) {
  const int b = blockIdx.x;
  if (b < 64) {                                   // prepe: 16384
    const int i = b*256 + threadIdx.x;
    const int j = i & 7, l = (i >> 3) & 63, ni = (i >> 9) & 3, nc = i >> 11;
    const int lm = l & 15, lk = l >> 4;
    wqe[i] = f2b(emb[(nc*64 + ni*16 + lm)*32 + lk*8 + j]);
    if (i < 512) {
      float s = 0.f;
      #pragma unroll
      for (int k = 0; k < 32; ++k) {
        const float f = b2f(f2b(emb[i*32 + k]));
        s = fmaf(f, f, s);
      }
      eng[i] = s;
    }
  } else if (b < 80) {                            // prep1v: 4096
    const int i = (b - 64)*256 + threadIdx.x;
    const int j = i & 7, l = (i >> 3) & 63, ni = (i >> 9) & 3, ks = i >> 11;
    const int k = ks*32 + (l >> 4)*8 + j;
    const int co = ni*16 + (l & 15);
    wq1[i] = (k < 48) ? f2b(ew1[co*48 + k]) : (unsigned short)0;
  } else if (b < 592) {                           // prep2v: 131072
    const int i = (b - 80)*256 + threadIdx.x;
    const int j = i & 7, l = (i >> 3) & 63, ni = (i >> 9) & 7, ks = i >> 12;
    const int lm = l & 15, lk = l >> 4;
    const int tap = ks >> 1, cc = ks & 1;
    const int co = ni*16 + lm, ci = cc*32 + lk*8 + j;
    wq2[i] = f2b(ew2[(co*64 + ci)*16 + tap]);
  } else if (b < 736) {                           // prep3v: 36864
    const int i = (b - 592)*256 + threadIdx.x;
    const int j = i & 7, l = (i >> 3) & 63, ni = (i >> 9) & 1, ks = i >> 10;
    const int lm = l & 15, lk = l >> 4;
    const int tap = ks >> 2, cf = ks & 3;
    const int co = ni*16 + lm, ci = cf*32 + lk*8 + j;
    wq3[i] = f2b(ew3[(co*128 + ci)*9 + tap]);
  } else if (b < 880) {                           // prep4v: 36864
    const int i = (b - 736)*256 + threadIdx.x;
    const int j = i & 7, l = (i >> 3) & 63, ni = (i >> 9) & 7, tap = i >> 12;
    const int lm = l & 15, lk = l >> 4;
    const int co = ni*16 + lm, ci = lk*8 + j;
    wq4[i] = f2b(dw1[(ci*128 + co)*9 + (8 - tap)]);
  } else if (b < 1392) {                          // prep5v: 131072
    const int i = (b - 880)*256 + threadIdx.x;
    const int j = i & 7, l = (i >> 3) & 63, ni = (i >> 9) & 3;
    const int ks = (i >> 11) & 15, p = i >> 15;
    const int lm = l & 15, lk = l >> 4;
    const int py = p >> 1, px = p & 1;
    const int a = ks >> 3, bb = (ks >> 2) & 1, cc = ks & 3;
    const int co = ni*16 + lm, ci = cc*32 + lk*8 + j;
    const int ky = 3 - 2*a - py, kx = 3 - 2*bb - px;
    wq5[i] = f2b(dw2[(ci*64 + co)*16 + ky*4 + kx]);
  } else {                                        // prep6: 16384
    const int i = (b - 1392)*256 + threadIdx.x;
    const int j = i & 7, l = (i >> 3) & 63, kc = (i >> 9) & 7, p = i >> 12;
    const int lm = l & 15, lk = l >> 4;
    const int a = kc >> 2, bb = (kc >> 1) & 1, ch = kc & 1;
    const int ci = ch*32 + lk*8 + j, co = lm;
    const int py = p >> 1, px = p & 1;
    const int ky = 2 - 2*a + (1 - py), kx = 2 - 2*bb + (1 - px);
    wq6[i] = (co < 3) ? f2b(dw3[(ci*3 + co)*16 + ky*4 + kx]) : (unsigned short)0;
  }
}

// ---- conv1 via MFMA: x NCHW fp32 [32,3,256,256] -> h1 NHWC bf16 ------------
__global__ __launch_bounds__(256) void conv1m_k(const float* __restrict__ x,
    const unsigned short* __restrict__ wv, const float* __restrict__ bias,
    unsigned short* __restrict__ out) {
  __shared__ __align__(16) short RAW[12*264];   // row g=ci*4+ky, idx=ix+4; 6336B
  __shared__ __align__(16) short IC[128*64];    // [ox][k] swizzled; 16384B
  const int wid = ((blockIdx.x & 7) << 9) + (blockIdx.x >> 3);
  const int q = wid & 127, n = wid >> 7;        // q = output row oy
  for (int i = threadIdx.x; i < 396; i += 256)
    *(short8*)&RAW[i*8] = (short8)(short)0;
  __syncthreads();
  for (int s = threadIdx.x; s < 768; s += 256) {   // 12 rows * 64 f32x4
    const int g = s >> 6, seg = s & 63;
    const int ci = g >> 2, ky = g & 3;
    const int iy = 2*q - 1 + ky;
    if (iy >= 0 && iy < 256) {
      const f32x4 v = *(const f32x4*)&x[((n*3 + ci)*256 + iy)*256 + seg*4];
      s16x4 sv;
      #pragma unroll
      for (int e = 0; e < 4; ++e) sv[e] = (short)f2b(v[e]);
      *(s16x4*)&RAW[g*264 + 4 + seg*4] = sv;
    }
  }
  __syncthreads();
  for (int s = threadIdx.x; s < 1024; s += 256) {
    const int kb = s & 7, ox = s >> 3;
    short8 v = (short8)(short)0;
    if (kb < 6) {
      const unsigned* u0 = (const unsigned*)&RAW[(2*kb  )*264 + 2*ox + 2];
      const unsigned* u1 = (const unsigned*)&RAW[(2*kb+1)*264 + 2*ox + 2];
      const unsigned a0 = u0[0], a1 = u0[1], a2 = u0[2];
      const unsigned b0 = u1[0], b1 = u1[1], b2 = u1[2];
      uint32x4 uv;
      uv[0] = (a0 >> 16) | (a1 << 16);
      uv[1] = (a1 >> 16) | (a2 << 16);
      uv[2] = (b0 >> 16) | (b1 << 16);
      uv[3] = (b1 >> 16) | (b2 << 16);
      v = __builtin_bit_cast(short8, uv);
    }
    const int bo = ((ox << 7) + (kb << 4)) ^ ((ox & 7) << 4);
    *(short8*)((char*)IC + bo) = v;
  }
  __syncthreads();
  const int w = threadIdx.x >> 6, l = threadIdx.x & 63;
  const int lm = l & 15, lk = l >> 4;
  f32x4 acc[2][4];
  #pragma unroll
  for (int mi = 0; mi < 2; ++mi)
    #pragma unroll
    for (int ni = 0; ni < 4; ++ni) acc[mi][ni] = (f32x4)0.0f;
  #pragma unroll
  for (int ks = 0; ks < 2; ++ks) {
    short8 bv[4];
    #pragma unroll
    for (int ni = 0; ni < 4; ++ni)
      bv[ni] = *(const short8*)(wv + (((ks*4 + ni)*64 + l) << 3));
    #pragma unroll
    for (int mi = 0; mi < 2; ++mi) {
      const int ox = w*32 + mi*16 + lm;
      const int bo = ((ox << 7) + (ks << 6) + (lk << 4)) ^ ((ox & 7) << 4);
      const short8 av = *(const short8*)((const char*)IC + bo);
      #pragma unroll
      for (int ni = 0; ni < 4; ++ni)
        acc[mi][ni] = __builtin_amdgcn_mfma_f32_16x16x32_bf16(
            __builtin_bit_cast(bf16x8, av),
            __builtin_bit_cast(bf16x8, bv[ni]),
            acc[mi][ni], 0, 0, 0);
    }
  }
  __syncthreads();            // frag reads done; reuse IC for output staging
  #pragma unroll
  for (int mi = 0; mi < 2; ++mi)
    #pragma unroll
    for (int ni = 0; ni < 4; ++ni) {
      const int co = ni*16 + lm;
      const float bv = bias[co];
      #pragma unroll
      for (int r = 0; r < 4; ++r) {
        const int ox = w*32 + mi*16 + lk*4 + r;
        const int bo = ((ox << 7) + 2*co) ^ ((ox & 7) << 4);
        *(short*)((char*)IC + bo) = (short)f2b(fmaxf(acc[mi][ni][r] + bv, 0.f));
      }
    }
  __syncthreads();
  const long ob = ((long)(n*128 + q)) * 8192;   // 128 ox * 64 co
  for (int s = threadIdx.x; s < 1024; s += 256) {
    const int kb = s & 7, ox = s >> 3;
    const int bo = ((ox << 7) + (kb << 4)) ^ ((ox & 7) << 4);
    *(short8*)&out[ob + ox*64 + kb*8] = *(const short8*)((const char*)IC + bo);
  }
}

// ---- conv2 via two-phase MFMA + async stage: h1 -> h2 ----------------------
//      LDS: 264 entries (r,idx) x 128B, slot s=p*4+lk stored at s^(E&7)
//      (convt2m-proven zero-conflict layout). K=(2ky+d)&7 compile-time.
#define C2_LOAD(c) \
  _Pragma("unroll") \
  for (int s = 0; s < 9; ++s) { \
    st[s] = (short8)(short)0; \
    if (goff[s] >= 0) st[s] = *(const short8*)(in + goff[s] + (c)*32); \
  }
#define C2_WRITE \
  _Pragma("unroll") \
  for (int s = 0; s < 9; ++s) \
    if (lb[s] >= 0) *(short8*)((char*)IL + lb[s]) = st[s];
#define C2_COMPUTE(c) \
  _Pragma("unroll") \
  for (int t = 0; t < 16; ++t) { \
    const int ky = t >> 2, kx = t & 3; \
    const int p = 1 - (kx & 1), d = kx >> 1; \
    const int K = (2*ky + d) & 7; \
    const short8 bv0 = *(const short8*)(wb + (t*2 + (c))*4096); \
    const short8 bv1 = *(const short8*)(wb + (t*2 + (c))*4096 + 512); \
    const int laneb = p ? (TK[K] ^ 0x40) : TK[K]; \
    const char* Ab = (const char*)IL + laneb; \
    const int imm0 = ky*8448 + d*128; \
    _Pragma("unroll") \
    for (int mi = 0; mi < 4; ++mi) { \
      const short8 av = *(const short8*)(Ab + imm0 + mi*2048); \
      acc[mi][0] = __builtin_amdgcn_mfma_f32_16x16x32_bf16( \
          __builtin_bit_cast(bf16x8, av), __builtin_bit_cast(bf16x8, bv0), \
          acc[mi][0], 0, 0, 0); \
      acc[mi][1] = __builtin_amdgcn_mfma_f32_16x16x32_bf16( \
          __builtin_bit_cast(bf16x8, av), __builtin_bit_cast(bf16x8, bv1), \
          acc[mi][1], 0, 0, 0); \
    } \
  }
__global__ __launch_bounds__(256) void conv2m_k(const unsigned short* __restrict__ in,
    const unsigned short* __restrict__ wv, const float* __restrict__ bias,
    unsigned short* __restrict__ out) {
  __shared__ short IL[264*64];         // 264 entries x 128 B, 33792 B
  const int wid = (blockIdx.x & 7)*256 + (blockIdx.x >> 3);
  const int q = wid & 63, n = wid >> 6;          // q = output row oy
  const int w = threadIdx.x >> 6, l = threadIdx.x & 63;
  const int lm = l & 15, lk = l >> 4;
  // per-lane swizzled A-read bases (slot = (p*4+lk) ^ ((lm+K)&7); p via ^0x40)
  int TK[8];
  #pragma unroll
  for (int K = 0; K < 8; ++K) {
    const int h = (lm + K) & 7;
    TK[K] = lm*128 + ((lk ^ (h & 3)) << 4) + ((h >> 2) << 6);
  }
  const unsigned short* wb = wv + w*1024 + l*8;  // + ks*4096 (+512 for ni=1)
  int goff[9], lb[9];
  #pragma unroll
  for (int s = 0; s < 9; ++s) {
    const int i = threadIdx.x + s*256;
    const int sl = i & 7, E = i >> 3;
    const int idx = E % 66, r = E / 66;
    const int p = sl >> 2, part = sl & 3;
    const int iy = 2*q - 1 + r, ix = 2*idx - p;
    const bool ok = (i < 2112) && iy >= 0 && iy < 128 && ix >= 0 && ix < 128;
    goff[s] = ok ? (((n*128 + iy)*128 + ix)*64 + part*8) : -1;
    lb[s]   = (i < 2112) ? (E*128 + ((sl ^ (E & 7)) << 4)) : -1;
  }
  f32x4 acc[4][2];
  #pragma unroll
  for (int mi = 0; mi < 4; ++mi)
    #pragma unroll
    for (int ni = 0; ni < 2; ++ni) acc[mi][ni] = (f32x4)0.0f;
  short8 st[9];
  C2_LOAD(0); C2_WRITE;
  __syncthreads();
  C2_LOAD(1);                          // issue phase-1 loads (in flight)
  C2_COMPUTE(0);
  __syncthreads();                     // phase-0 LDS reads done
  C2_WRITE;                            // waits vmcnt for st, writes LDS
  __syncthreads();
  C2_COMPUTE(1);
  // coalesced epilogue: PB[64 ox][144 shorts] over IL (18432 B)
  __syncthreads();                     // compute(1) IL reads done
  short* PB = (short*)IL;
  #pragma unroll
  for (int mi = 0; mi < 4; ++mi)
    #pragma unroll
    for (int r = 0; r < 4; ++r) {
      const int ox = mi*16 + lk*4 + r;
      #pragma unroll
      for (int ni = 0; ni < 2; ++ni) {
        const int co = (w*2 + ni)*16 + lm;
        PB[ox*144 + co] = (short)f2b(fmaxf(acc[mi][ni][r] + bias[co], 0.f));
      }
    }
  __syncthreads();
  {
    const int pos = threadIdx.x >> 2, coq = (threadIdx.x & 3) << 5;
    const long ob = ((long)((n*64 + q)*64 + pos))*128 + coq;
    #pragma unroll
    for (int u2 = 0; u2 < 4; ++u2)
      *(short8*)&out[ob + u2*8] = *(const short8*)&PB[pos*144 + coq + u2*8];
  }
}

// ---- conv3 + fused VQ: h2 NHWC bf16 [32,64,64,128] -> zq f32 + loss --------
#define C3_LOAD(c) \
  _Pragma("unroll") \
  for (int s = 0; s < 9; ++s) { \
    st[s] = (short8)(short)0; \
    if (goff[s] >= 0) st[s] = *(const short8*)(in + goff[s] + (c)*64); \
  }
#define C3_WRITE \
  _Pragma("unroll") \
  for (int s = 0; s < 9; ++s) \
    if (lb[s] >= 0) *(short8*)((char*)IL + lb[s]) = st[s];
#define C3_COMPUTE(c) \
  _Pragma("unroll") \
  for (int u = 0; u < 18; ++u) { \
    const int tap = u >> 1, cc = u & 1; \
    const int ky = tap / 3, kx = tap % 3; \
    const int ks = tap*4 + (c)*2 + cc; \
    const short8 bv0 = *(const short8*)(wb + ks*1024); \
    const short8 bv1 = *(const short8*)(wb + ks*1024 + 512); \
    const char* Ab = (const char*)IL + (Wc[kx][cc]); \
    const int imm0 = ky*8448; \
    _Pragma("unroll") \
    for (int mi = 0; mi < 2; ++mi) { \
      const short8 av = *(const short8*)(Ab + imm0 + mi*2048); \
      acc[mi][0] = __builtin_amdgcn_mfma_f32_16x16x32_bf16( \
          __builtin_bit_cast(bf16x8, av), __builtin_bit_cast(bf16x8, bv0), \
          acc[mi][0], 0, 0, 0); \
      acc[mi][1] = __builtin_amdgcn_mfma_f32_16x16x32_bf16( \
          __builtin_bit_cast(bf16x8, av), __builtin_bit_cast(bf16x8, bv1), \
          acc[mi][1], 0, 0, 0); \
    } \
  }
__global__ __launch_bounds__(256) void conv3v_k(const unsigned short* __restrict__ in,
    const unsigned short* __restrict__ wv, const float* __restrict__ bias,
    const unsigned short* __restrict__ wqe, const float* __restrict__ eng,
    const float* __restrict__ emb, float* __restrict__ zq,
    float* __restrict__ part) {
  __shared__ short IL[4*66*64];        // 33792 B; unions below after compute
  const int wid = (blockIdx.x & 7)*128 + (blockIdx.x >> 3);
  const int q = wid & 31, n = wid >> 5;          // oy0 = 2q
  const int w = threadIdx.x >> 6, l = threadIdx.x & 63;
  const int lm = l & 15, lk = l >> 4;
  const int row = w >> 1, oxb = (w & 1) * 32;
  int goff[9], lb[9];
  #pragma unroll
  for (int s = 0; s < 9; ++s) {
    const int i = threadIdx.x + s*256;
    const int part_ = i & 7, e = i >> 3;
    const int col = e % 66, r = e / 66;
    const int iy = 2*q - 1 + r, ix = col - 1;
    const bool ok = (i < 2112) && iy >= 0 && iy < 64 && ix >= 0 && ix < 64;
    goff[s] = ok ? (((n*64 + iy)*64 + ix)*128 + part_*8) : -1;
    lb[s]   = (i < 2112) ? ((e << 7) + ((part_ << 4) ^ ((col & 7) << 4))) : -1;
  }
  int Wc[3][2];
  #pragma unroll
  for (int kx = 0; kx < 3; ++kx) {
    const int e = oxb + lm + kx;
    Wc[kx][0] = row*8448 + (e << 7) + ((lk << 4) ^ ((e & 7) << 4));
    Wc[kx][1] = Wc[kx][0] ^ 0x40;
  }
  const unsigned short* wb = wv + l*8;           // + ks*1024 + ni*512
  f32x4 acc[2][2];
  #pragma unroll
  for (int mi = 0; mi < 2; ++mi)
    #pragma unroll
    for (int ni = 0; ni < 2; ++ni) acc[mi][ni] = (f32x4)0.0f;
  short8 st[9];
  C3_LOAD(0); C3_WRITE;
  __syncthreads();
  C3_LOAD(1);
  C3_COMPUTE(0);
  __syncthreads();
  C3_WRITE;
  __syncthreads();
  C3_COMPUTE(1);
  // ---- fused VQ ----
  __syncthreads();                               // all IL reads done
  short* ZB  = (short*)IL;                       // [128][40] bf16, 10240 B
  float* ZF  = (float*)((char*)IL + 10240);      // [128][36] f32, 18432 B
  int*  bidx = (int*)((char*)IL + 28672);        // 128 ints
  float* red = (float*)((char*)IL + 29184);      // 256 floats
  #pragma unroll
  for (int mi = 0; mi < 2; ++mi)
    #pragma unroll
    for (int ni = 0; ni < 2; ++ni) {
      const int co = ni*16 + lm;
      const float bv = bias[co];
      #pragma unroll
      for (int r = 0; r < 4; ++r) {
        const int pos = row*64 + oxb + mi*16 + lk*4 + r;
        const float v = fmaxf(acc[mi][ni][r] + bv, 0.f);
        ZB[pos*40 + co] = (short)f2b(v);
        ZF[pos*36 + co] = v;
      }
    }
  __syncthreads();
  short8 av[2];
  #pragma unroll
  for (int mi = 0; mi < 2; ++mi)
    av[mi] = *(const short8*)&ZB[(row*64 + oxb + mi*16 + lm)*40 + lk*8];
  float bd[2][4]; int bj[2][4];
  #pragma unroll
  for (int mi = 0; mi < 2; ++mi)
    #pragma unroll
    for (int r = 0; r < 4; ++r) { bd[mi][r] = 1e30f; bj[mi][r] = 0; }
  for (int nc = 0; nc < 8; ++nc) {               // chunks of 64 codes
    f32x4 a2[2][4];
    #pragma unroll
    for (int mi = 0; mi < 2; ++mi)
      #pragma unroll
      for (int ni = 0; ni < 4; ++ni) a2[mi][ni] = (f32x4)0.0f;
    #pragma unroll
    for (int ni = 0; ni < 4; ++ni) {
      const short8 bv = *(const short8*)(wqe + (((nc*4 + ni)*64 + l) << 3));
      #pragma unroll
      for (int mi = 0; mi < 2; ++mi)
        a2[mi][ni] = __builtin_amdgcn_mfma_f32_16x16x32_bf16(
            __builtin_bit_cast(bf16x8, av[mi]),
            __builtin_bit_cast(bf16x8, bv),
            a2[mi][ni], 0, 0, 0);
    }
    #pragma unroll
    for (int ni = 0; ni < 4; ++ni) {
      const int j = nc*64 + ni*16 + lm;
      const float e_n = eng[j];
      #pragma unroll
      for (int mi = 0; mi < 2; ++mi)
        #pragma unroll
        for (int r = 0; r < 4; ++r) {
          const float d = fmaf(-2.f, a2[mi][ni][r], e_n);
          if (d < bd[mi][r]) { bd[mi][r] = d; bj[mi][r] = j; }
        }
    }
  }
  #pragma unroll
  for (int mi = 0; mi < 2; ++mi)
    #pragma unroll
    for (int r = 0; r < 4; ++r) {
      float d = bd[mi][r]; int j = bj[mi][r];
      #pragma unroll
      for (int off = 1; off < 16; off <<= 1) {
        const float od = __shfl_xor(d, off);
        const int   oj = __shfl_xor(j, off);
        if (od < d || (od == d && oj < j)) { d = od; j = oj; }
      }
      if (lm == 0) bidx[row*64 + oxb + mi*16 + lk*4 + r] = j;
    }
  __syncthreads();
  const int pl = threadIdx.x >> 1, hf = (threadIdx.x & 1) * 16;
  const int code = bidx[pl];
  const int oy2 = 2*q + (pl >> 6), ox2 = pl & 63;
  const long zqo = ((long)((n*64 + oy2)*64 + ox2)) * 32 + hf;
  float se = 0.f;
  #pragma unroll
  for (int qq = 0; qq < 4; ++qq) {
    const f32x4 ev = *(const f32x4*)&emb[code*32 + hf + qq*4];
    const f32x4 zv = *(const f32x4*)&ZF[pl*36 + hf + qq*4];
    *(f32x4*)&zq[zqo + qq*4] = ev;
    const f32x4 df = ev - zv;
    #pragma unroll
    for (int e = 0; e < 4; ++e) se = fmaf(df[e], df[e], se);
  }
  red[threadIdx.x] = se; __syncthreads();
  for (int s2 = 128; s2 > 0; s2 >>= 1) {
    if (threadIdx.x < s2) red[threadIdx.x] += red[threadIdx.x + s2];
    __syncthreads();
  }
  if (threadIdx.x == 0) part[blockIdx.x] = red[0];
}

// ---- d1 convT via MFMA: zq f32 [131072,32] -> d1 NHWC bf16 [32,64,64,128]
__global__ __launch_bounds__(256) void d1m_k(const float* __restrict__ in,
    const unsigned short* __restrict__ wv, const float* __restrict__ bias,
    unsigned short* __restrict__ out) {
  __shared__ short IL[264*40];         // [r*66+col][40-short stride], 21120 B
  const int wid = (blockIdx.x & 7)*128 + (blockIdx.x >> 3);
  const int q = wid & 31, n = wid >> 5;
  const int w = threadIdx.x >> 6, l = threadIdx.x & 63;
  const int lm = l & 15, lk = l >> 4;
  const int row = w >> 1, oxb = (w & 1) * 32;
  for (int i = threadIdx.x; i < 1056; i += 256) {  // 264 entries * 4 parts
    const int part = i & 3, e = i >> 2;
    const int col = e % 66, r = e / 66;
    const int iy = 2*q - 1 + r, ix = col - 1;
    short8 v = (short8)(short)0;
    if (iy >= 0 && iy < 64 && ix >= 0 && ix < 64) {
      const float* p = in + (((long)((n*64 + iy)*64 + ix)) * 32 + part*8);
      const f32x4 f0 = *(const f32x4*)p;
      const f32x4 f1 = *(const f32x4*)(p + 4);
      #pragma unroll
      for (int e2 = 0; e2 < 4; ++e2) {
        v[e2]     = (short)f2b(f0[e2]);
        v[e2 + 4] = (short)f2b(f1[e2]);
      }
    }
    *(short8*)&IL[e*40 + part*8] = v;
  }
  const unsigned short* wb = wv + l*8;             // + (tap*8+ni)*512
  int Wd[3];
  #pragma unroll
  for (int kx = 0; kx < 3; ++kx)
    Wd[kx] = row*5280 + (oxb + lm + kx)*80 + lk*16;   // bytes
  __syncthreads();
  f32x4 acc[2][8];
  #pragma unroll
  for (int mi = 0; mi < 2; ++mi)
    #pragma unroll
    for (int ni = 0; ni < 8; ++ni) acc[mi][ni] = (f32x4)0.0f;
  #pragma unroll
  for (int tap = 0; tap < 9; ++tap) {
    const int ky = tap / 3, kx = tap % 3;
    short8 bv[8];
    #pragma unroll
    for (int ni = 0; ni < 8; ++ni)
      bv[ni] = *(const short8*)(wb + (tap*8 + ni)*512);
    const char* Ab = (const char*)IL + Wd[kx];
    const int imm0 = ky*5280;
    #pragma unroll
    for (int mi = 0; mi < 2; ++mi) {
      const short8 av = *(const short8*)(Ab + imm0 + mi*1280);
      #pragma unroll
      for (int ni = 0; ni < 8; ++ni)
        acc[mi][ni] = __builtin_amdgcn_mfma_f32_16x16x32_bf16(
            __builtin_bit_cast(bf16x8, av),
            __builtin_bit_cast(bf16x8, bv[ni]),
            acc[mi][ni], 0, 0, 0);
    }
  }
  // coalesced epilogue: 2 row passes, PB[64 ox][144 shorts] over IL (18432 B)
  short* PB = (short*)IL;
  #pragma unroll
  for (int rp = 0; rp < 2; ++rp) {
    __syncthreads();                   // IL reads / prior pass reads done
    if (row == rp) {
      #pragma unroll
      for (int mi = 0; mi < 2; ++mi)
        #pragma unroll
        for (int r = 0; r < 4; ++r) {
          const int ox = oxb + mi*16 + lk*4 + r;
          #pragma unroll
          for (int ni = 0; ni < 8; ++ni) {
            const int co = ni*16 + lm;
            PB[ox*144 + co] = (short)f2b(fmaxf(acc[mi][ni][r] + bias[co], 0.f));
          }
        }
    }
    __syncthreads();
    const int pos = threadIdx.x >> 2, coq = (threadIdx.x & 3) << 5;
    const long ob = ((long)((n*64 + 2*q + rp)*64 + pos))*128 + coq;
    #pragma unroll
    for (int u2 = 0; u2 < 4; ++u2)
      *(short8*)&out[ob + u2*8] = *(const short8*)&PB[pos*144 + coq + u2*8];
  }
}

// ---- d2 convT: q-pair / 8-wave merged-parity MFMA + async stage ------------
__device__ __forceinline__ int ct2_goff(int i, int q0, int n) {
  const int part = i & 7, e = i >> 3;
  const int col = e % 66, r = e / 66;
  const int iy = q0 - 1 + r, ix = col - 1;
  return (i < 2112 && iy >= 0 && iy < 64 && ix >= 0 && ix < 64)
         ? (((n*64 + iy)*64 + ix)*128 + part*8) : -1;
}
__device__ __forceinline__ int ct2_lb(int i) {
  const int part = i & 7, e = i >> 3;
  const int col = e % 66;
  return (i < 2112) ? ((e << 7) + ((part << 4) ^ ((col & 7) << 4))) : -1;
}
#define CT2_LOAD(c) \
  _Pragma("unroll") \
  for (int s = 0; s < 5; ++s) { \
    const int g = ct2_goff(tid + s*512, q0, n); \
    st[s] = (short8)(short)0; \
    if (g >= 0) st[s] = *(const short8*)(in + g + (c)*64); \
  }
#define CT2_WRITE \
  _Pragma("unroll") \
  for (int s = 0; s < 5; ++s) { \
    const int b_ = ct2_lb(tid + s*512); \
    if (b_ >= 0) *(short8*)((char*)IL + b_) = st[s]; \
  }
#define CT2_COMPUTE(c) \
  _Pragma("unroll") \
  for (int u = 0; u < 8; ++u) { \
    const int a = u >> 2, b = (u >> 1) & 1, c1 = u & 1; \
    const int ks = (a << 3) | (b << 2) | (2*(c) + c1); \
    short8 bv[4]; \
    _Pragma("unroll") \
    for (int ni = 0; ni < 4; ++ni) \
      bv[ni] = *(const short8*)(wb + ks*2048 + ni*512); \
    const char* Ab = (const char*)IL + (pyb + Wb[b][c1]); \
    const int imm0 = a*8448; \
    _Pragma("unroll") \
    for (int mi = 0; mi < 4; ++mi) { \
      const short8 av = *(const short8*)(Ab + imm0 + mi*2048); \
      _Pragma("unroll") \
      for (int ni = 0; ni < 4; ++ni) \
        acc[mi][ni] = __builtin_amdgcn_mfma_f32_16x16x32_bf16( \
            __builtin_bit_cast(bf16x8, av), \
            __builtin_bit_cast(bf16x8, bv[ni]), \
            acc[mi][ni], 0, 0, 0); \
    } \
  }
__global__ __launch_bounds__(512, 4) void convt2m_k(
    const unsigned short* __restrict__ in,
    const unsigned short* __restrict__ wv, const float* __restrict__ bias,
    unsigned short* __restrict__ out) {
  __shared__ short IL[4*66*64];        // 264 entries x 128 B, 33792 B
  const int wid = (blockIdx.x & 7)*128 + (blockIdx.x >> 3);
  const int qp = wid & 31, n = wid >> 5;
  const int q0 = 2*qp;
  const int tid = threadIdx.x;
  const int w = tid >> 6, l = tid & 63;
  const int qi = w >> 2;
  const int py = (w >> 1) & 1, px = w & 1;
  const int lm = l & 15, lk = l >> 4;
  int Wb[2][2];
  #pragma unroll
  for (int b = 0; b < 2; ++b) {
    const int e = lm + px + b;
    Wb[b][0] = (e << 7) + ((lk << 4) ^ ((e & 7) << 4));
    Wb[b][1] = Wb[b][0] ^ 0x40;
  }
  const int pyb = (py + qi) * 8448;                // staged-row base
  const unsigned short* wb = wv + (w & 3)*32768 + l*8;   // parity weights
  f32x4 acc[4][4];
  #pragma unroll
  for (int mi = 0; mi < 4; ++mi)
    #pragma unroll
    for (int ni = 0; ni < 4; ++ni) acc[mi][ni] = (f32x4)0.0f;
  short8 st[5];
  CT2_LOAD(0); CT2_WRITE;
  __syncthreads();
  CT2_LOAD(1);                         // issue phase-1 loads (in flight)
  CT2_COMPUTE(0);
  __syncthreads();                     // phase-0 LDS reads done
  CT2_WRITE;                           // waits vmcnt, writes LDS
  __syncthreads();
  CT2_COMPUTE(1);
  // coalesced epilogue: 4 passes (qq x co-half), PB[256 pos][40 shorts]
  short* PB = (short*)IL;
  #pragma unroll
  for (int qq = 0; qq < 2; ++qq)
    #pragma unroll
    for (int half = 0; half < 2; ++half) {
      __syncthreads();                 // IL / prior-pass reads done
      if (qi == qq) {
        #pragma unroll
        for (int mi = 0; mi < 4; ++mi)
          #pragma unroll
          for (int r = 0; r < 4; ++r) {
            const int ox = 2*(mi*16 + lk*4 + r) + px;
            const int pos = py*128 + ox;
            #pragma unroll
            for (int nn = 0; nn < 2; ++nn) {
              const int co = (half*2 + nn)*16 + lm;
              PB[pos*40 + (co & 31)] =
                  (short)f2b(fmaxf(acc[mi][half*2 + nn][r] + bias[co], 0.f));
            }
          }
      }
      __syncthreads();
      const int pos = tid >> 1, hh = (tid & 1) << 4;
      const long ob = ((long)((n*128 + 2*(q0 + qq) + (pos >> 7))*128
                              + (pos & 127)))*64 + half*32 + hh;
      *(short8*)&out[ob]     = *(const short8*)&PB[pos*40 + hh];
      *(short8*)&out[ob + 8] = *(const short8*)&PB[pos*40 + hh + 8];
    }
}

__global__ __launch_bounds__(256) void loss_k(const float* __restrict__ part,
                                              float* __restrict__ out) {
  __shared__ float red[256];
  const int t = threadIdx.x;
  float s = 0.f;
  #pragma unroll
  for (int q = 0; q < 4; ++q) s += part[t + q*256];   // 1024 partials
  red[t] = s; __syncthreads();
  for (int st = 128; st > 0; st >>= 1) {
    if (t < st) red[t] += red[t + st];
    __syncthreads();
  }
  if (t == 0) out[0] = red[0] * (1.25f / (131072.f * 32.f));
}

// ---- convt3 via MFMA: d2 NHWC bf16 [32,128,128,64] -> x_recon NCHW fp32 ----
__global__ __launch_bounds__(256) void convt3m_k(const unsigned short* __restrict__ in,
    const unsigned short* __restrict__ wq6, const float* __restrict__ bias,
    float* __restrict__ out) {
  __shared__ short8 IL[3*8*66];      // [(r*8+c8)*66 + ixl], 25344 B
  const int h = blockIdx.x & 1, q = (blockIdx.x >> 1) & 127, n = blockIdx.x >> 8;
  for (int i = threadIdx.x; i < 1584; i += 256) {   // 3*66*8
    const int c8 = i & 7, t = i >> 3, ixl = t % 66, r = t / 66;
    const int iy = q - 1 + r, ix = h*64 - 1 + ixl;
    short8 v = (short8)(short)0;
    if (iy >= 0 && iy < 128 && ix >= 0 && ix < 128)
      v = *(const short8*)(in + (((long)(n*128 + iy)*128 + ix)*64 + c8*8));
    IL[(r*8 + c8)*66 + ixl] = v;
  }
  const int w = threadIdx.x >> 6, l = threadIdx.x & 63;
  const int py = w >> 1, px = w & 1;
  const int lm = l & 15, lk = l >> 4;
  short8 bfrag[8];
  #pragma unroll
  for (int kc = 0; kc < 8; ++kc)
    bfrag[kc] = *(const short8*)(wq6 + (((w*8 + kc)*64 + l) << 3));
  __syncthreads();
  f32x4 acc[4];
  #pragma unroll
  for (int mi = 0; mi < 4; ++mi) acc[mi] = (f32x4)0.0f;
  #pragma unroll
  for (int kc = 0; kc < 8; ++kc) {
    const int a = kc >> 2, b = (kc >> 1) & 1, ch = kc & 1;
    const int base = (((py + a)*8 + ch*4 + lk)*66) + px + b;   // + ixl(xq)
    #pragma unroll
    for (int mi = 0; mi < 4; ++mi) {
      const short8 av = *(const short8*)&IL[base + mi*16 + lm];
      acc[mi] = __builtin_amdgcn_mfma_f32_16x16x32_bf16(
          __builtin_bit_cast(bf16x8, av),
          __builtin_bit_cast(bf16x8, bfrag[kc]),
          acc[mi], 0, 0, 0);
    }
  }
  // coalesced epilogue via LDS (768 floats over IL)
  __syncthreads();                     // IL reads done
  float* PB3 = (float*)IL;
  if (lm < 3) {
    const float bv = bias[lm];
    #pragma unroll
    for (int mi = 0; mi < 4; ++mi)
      #pragma unroll
      for (int r = 0; r < 4; ++r) {
        const int xq = mi*16 + lk*4 + r;
        PB3[(lm*2 + py)*128 + 2*xq + px] = acc[mi][r] + bv;
      }
  }
  __syncthreads();
  for (int t = threadIdx.x; t < 768; t += 256) {
    const int co = t >> 8, rem = t & 255, pyl = rem >> 7, xx = rem & 127;
    out[((long)(n*3 + co))*65536 + (2*q + pyl)*256 + h*128 + xx] = PB3[t];
  }
}

extern "C" void kernel_launch(void* const* d_in, const int* in_sizes, int n_in,
                              void* d_out, int out_size, void* d_ws, size_t ws_size,
                              hipStream_t stream) {
  const float* x   = (const float*)d_in[0];
  const float* ew1 = (const float*)d_in[1];  const float* eb1 = (const float*)d_in[2];
  const float* ew2 = (const float*)d_in[3];  const float* eb2 = (const float*)d_in[4];
  const float* ew3 = (const float*)d_in[5];  const float* eb3 = (const float*)d_in[6];
  const float* emb = (const float*)d_in[7];
  const float* dw1 = (const float*)d_in[8];  const float* db1 = (const float*)d_in[9];
  const float* dw2 = (const float*)d_in[10]; const float* db2 = (const float*)d_in[11];
  const float* dw3 = (const float*)d_in[12]; const float* db3 = (const float*)d_in[13];
  float* out = (float*)d_out;

  uint8_t* w8 = (uint8_t*)d_ws;
  unsigned short* h1 = (unsigned short*)w8;
  unsigned short* h2 = (unsigned short*)(w8 + 67108864);
  uint8_t* zr = w8 + 100663296;
  float* zq  = (float*)(w8 + 117440512);
  unsigned short* wqe = (unsigned short*)zr;                  // 32768 B
  float* eng = (float*)(zr + 32768);                          // 2048 B
  float* part = (float*)(zr + 36864);                         // 4096 B
  unsigned short* wq3 = (unsigned short*)(zr + 40960);        // 73728 B
  unsigned short* wq4 = (unsigned short*)(zr + 131072);       // 73728 B
  unsigned short* wq5 = (unsigned short*)(zr + 262144);       // 262144 B
  unsigned short* wq6 = (unsigned short*)(zr + 524288);       // 32768 B
  unsigned short* wq2 = (unsigned short*)(w8 + 117440512);            // 262144 B
  unsigned short* wq1 = (unsigned short*)(w8 + 117440512 + 335872);   // 8192 B
  unsigned short* d1 = h2;
  unsigned short* d2 = h1;

  // all weight/embed prep in one launch
  prepall_k<<<dim3(1456),256,0,stream>>>(ew1, ew2, ew3, dw1, dw2, dw3, emb,
                                         wq1, wq2, wq3, wq4, wq5, wq6, wqe, eng);
  // encoder + fused VQ
  conv1m_k<<<dim3(4096),256,0,stream>>>(x, wq1, eb1, h1);
  conv2m_k<<<dim3(2048),256,0,stream>>>(h1, wq2, eb2, h2);
  conv3v_k<<<dim3(1024),256,0,stream>>>(h2, wq3, eb3, wqe, eng, emb, zq, part);
  loss_k<<<dim3(1),256,0,stream>>>(part, out + 6291456);
  // decoder
  d1m_k<<<dim3(1024),256,0,stream>>>(zq, wq4, db1, d1);
  convt2m_k<<<dim3(1024),512,0,stream>>>(d1, wq5, db2, d2);
  convt3m_k<<<dim3(8192),256,0,stream>>>(d2, wq6, db3, out);
}